// Round 7
// baseline (135.676 us; speedup 1.0000x reference)
//
#include <hip/hip_runtime.h>

// Problem constants
constexpr int B_ = 32, C_ = 256, L_ = 1024, NE = 1024;
constexpr int NPTS = B_ * L_;            // 32768 points
// d_out flat float32 layout (reference return order)
constexpr long long LOSS_OFF = 0;
constexpr long long ZQ_OFF   = 1;                         // 8,388,608 elems
constexpr long long PERP_OFF = 1 + 8388608;               // 8388609
constexpr long long OH_OFF   = PERP_OFF + 1;              // 8388610
constexpr long long IDX_OFF  = OH_OFF + 33554432LL;       // 41943042
// workspace byte offsets
constexpr size_t WS_IDX = 0;            // int[32768]
constexpr size_t WS_CNT = 131072;       // uint[1024]
constexpr size_t WS_LP  = 135168;       // float[1024]
constexpr size_t WS_E2  = 139264;       // float[1024]

constexpr float MARGIN = 7e-4f;         // >= 2*(fp16 dot err) + d-quantization slack

typedef _Float16 f16x8 __attribute__((ext_vector_type(8)));
typedef float    f32x4 __attribute__((ext_vector_type(4)));

__device__ inline unsigned fkey(float f) {
  unsigned u = __float_as_uint(f);
  return (u & 0x80000000u) ? ~u : (u | 0x80000000u);
}
__device__ inline float unfkey(unsigned k) {
  unsigned u = (k & 0x80000000u) ? (k ^ 0x80000000u) : ~k;
  return __uint_as_float(u);
}

// ---- prep: e2 (fp64->fp32), codebook fp32->fp16, zero counts. One dispatch. ----
__global__ __launch_bounds__(256) void k_prep(const float* __restrict__ emb,
                                              _Float16* __restrict__ ehl,
                                              float* __restrict__ e2,
                                              unsigned* __restrict__ counts) {
  const int tid = threadIdx.x, bid = blockIdx.x;
  const int w = tid >> 6, lane = tid & 63;
  const int code = bid * 4 + w;
  float4 v = reinterpret_cast<const float4*>(emb + (size_t)code * C_)[lane];
  _Float16 h0 = (_Float16)v.x, h1 = (_Float16)v.y;
  _Float16 h2 = (_Float16)v.z, h3 = (_Float16)v.w;
  unsigned u0 = (unsigned)__builtin_bit_cast(unsigned short, h0) |
                ((unsigned)__builtin_bit_cast(unsigned short, h1) << 16);
  unsigned u1 = (unsigned)__builtin_bit_cast(unsigned short, h2) |
                ((unsigned)__builtin_bit_cast(unsigned short, h3) << 16);
  reinterpret_cast<uint2*>(ehl)[code * 64 + lane] = make_uint2(u0, u1);
  // fp64 accumulate -> fp32 (any fp64 order rounds to the same fp32)
  double s = 0.0;
  s += (double)v.x * (double)v.x;
  s += (double)v.y * (double)v.y;
  s += (double)v.z * (double)v.z;
  s += (double)v.w * (double)v.w;
#pragma unroll
  for (int off = 32; off > 0; off >>= 1) s += __shfl_down(s, off);
  if (lane == 0) e2[code] = (float)s;
  if (tid < 4) counts[bid * 4 + tid] = 0u;
}

// ---- MFMA fp16 screen: 64 points x 1024 codes per block, 512 blocks (2/CU).
// B fragments direct from global (L2-hot); A in LDS with XOR slot swizzle.
// Same per-point s arithmetic as the R4-R6 verified screens -> same candidates.
__global__ __launch_bounds__(512, 2) void k_screen(const float* __restrict__ z,
                                                   const _Float16* __restrict__ ehl,
                                                   const float* __restrict__ e2g,
                                                   unsigned short* __restrict__ cand_codes,
                                                   unsigned* __restrict__ cand_cnt) {
  __shared__ _Float16 Az[64 * 256];           // 32 KB
  __shared__ unsigned minkey[64];
  __shared__ unsigned ccnt[64];
  __shared__ unsigned short cand[64 * 32];    // 4 KB

  const int tid  = threadIdx.x;
  const int lane = tid & 63;
  const int wid  = tid >> 6;
  const int wr   = wid >> 2;          // 0..1 point half (32 pts)
  const int wc   = wid & 3;           // 0..3 code quarter (of chunk)
  const int l15  = lane & 15;
  const int lhi  = lane >> 4;         // 0..3
  const int n0   = blockIdx.x * 64;
  const int b    = blockIdx.x >> 4;
  const int l0   = (blockIdx.x & 15) << 6;

  const uint4* ehl4 = reinterpret_cast<const uint4*>(ehl);

  // A transpose+convert: z[b][k][l0+l'] fp32 -> Az[p][k] f16, XOR slot swizzle
  {
    const float4* z4 = reinterpret_cast<const float4*>(z + (size_t)b * (C_ * L_) + l0);
    const int l4 = tid & 15;          // 16 l-groups of 4
    const int kp = tid >> 4;          // 0..31
#pragma unroll
    for (int rr = 0; rr < 4; ++rr) {
      const int k0 = rr * 64 + kp * 2;
      float4 a0 = z4[(size_t)k0 * (L_ / 4) + l4];
      float4 a1 = z4[(size_t)(k0 + 1) * (L_ / 4) + l4];
      const float av0[4] = {a0.x, a0.y, a0.z, a0.w};
      const float av1[4] = {a1.x, a1.y, a1.z, a1.w};
#pragma unroll
      for (int j = 0; j < 4; ++j) {
        _Float16 h0 = (_Float16)av0[j];
        _Float16 h1 = (_Float16)av1[j];
        unsigned pk = (unsigned)__builtin_bit_cast(unsigned short, h0) |
                      ((unsigned)__builtin_bit_cast(unsigned short, h1) << 16);
        const int p = l4 * 4 + j;
        const int slot = k0 >> 3;
        const int addr = p * 256 + ((slot ^ (p & 31)) << 3) + (k0 & 7);
        *reinterpret_cast<unsigned*>(&Az[addr]) = pk;
      }
    }
  }
  if (tid < 64) { minkey[tid] = 0xFFFFFFFFu; ccnt[tid] = 0u; }
  __syncthreads();

  f32x4 acc[2][4];
#pragma unroll
  for (int i = 0; i < 2; ++i)
#pragma unroll
    for (int j = 0; j < 4; ++j) acc[i][j] = (f32x4){0.f, 0.f, 0.f, 0.f};

  for (int ph = 0; ph < 8; ++ph) {
    const int cc = ph >> 1;
    const int kh = ph & 1;
#pragma unroll
    for (int s = 0; s < 4; ++s) {
      const int slotA = kh * 16 + s * 4 + lhi;
      f16x8 bfr[4];
#pragma unroll
      for (int tj = 0; tj < 4; ++tj)
        bfr[tj] = __builtin_bit_cast(f16x8,
            ehl4[(size_t)(cc * 256 + wc * 64 + tj * 16 + l15) * 32 +
                 kh * 16 + s * 4 + lhi]);
      f16x8 afr[2];
#pragma unroll
      for (int ti = 0; ti < 2; ++ti) {
        const int pA = wr * 32 + ti * 16 + l15;
        const int swzA = slotA ^ ((ti << 4) ^ l15);
        afr[ti] = *reinterpret_cast<const f16x8*>(&Az[pA * 256 + swzA * 8]);
      }
#pragma unroll
      for (int ti = 0; ti < 2; ++ti)
#pragma unroll
        for (int tj = 0; tj < 4; ++tj)
          acc[ti][tj] = __builtin_amdgcn_mfma_f32_16x16x32_f16(
              afr[ti], bfr[tj], acc[ti][tj], 0, 0, 0);
    }
    if (kh == 1) {
      float e2r[4];
#pragma unroll
      for (int tj = 0; tj < 4; ++tj)
        e2r[tj] = e2g[cc * 256 + wc * 64 + tj * 16 + l15];
#pragma unroll
      for (int ti = 0; ti < 2; ++ti) {
#pragma unroll
        for (int r = 0; r < 4; ++r) {
          float m = e2r[0] - 2.0f * acc[ti][0][r];
#pragma unroll
          for (int tj = 1; tj < 4; ++tj) {
            float v = e2r[tj] - 2.0f * acc[ti][tj][r];
            m = fminf(m, v);
          }
          m = fminf(m, __shfl_xor(m, 1));
          m = fminf(m, __shfl_xor(m, 2));
          m = fminf(m, __shfl_xor(m, 4));
          m = fminf(m, __shfl_xor(m, 8));
          if (l15 == 0) {
            const int p = wr * 32 + ti * 16 + lhi * 4 + r;
            atomicMin(&minkey[p], fkey(m));
          }
        }
      }
      __syncthreads();   // chunk-cc mins visible; later chunks only shrink thr
#pragma unroll
      for (int ti = 0; ti < 2; ++ti) {
#pragma unroll
        for (int r = 0; r < 4; ++r) {
          const int p = wr * 32 + ti * 16 + lhi * 4 + r;
          const float thr = unfkey(minkey[p]) + MARGIN;
#pragma unroll
          for (int tj = 0; tj < 4; ++tj) {
            float s = e2r[tj] - 2.0f * acc[ti][tj][r];
            if (s <= thr) {
              unsigned pos = atomicAdd(&ccnt[p], 1u);
              if (pos < 32u)
                cand[p * 32 + pos] = (unsigned short)(cc * 256 + wc * 64 + tj * 16 + l15);
            }
          }
        }
      }
#pragma unroll
      for (int i = 0; i < 2; ++i)
#pragma unroll
        for (int j = 0; j < 4; ++j) acc[i][j] = (f32x4){0.f, 0.f, 0.f, 0.f};
    }
  }
  __syncthreads();

  if (tid < 64) {
    const int n = n0 + tid;
    cand_cnt[n] = ccnt[tid];
    const unsigned* src = reinterpret_cast<const unsigned*>(&cand[tid * 32]);
    unsigned* dst = reinterpret_cast<unsigned*>(cand_codes) + (size_t)n * 16;
#pragma unroll
    for (int q = 0; q < 16; ++q) dst[q] = src[q];
  }
}

// ---- fused post: exact re-rank + z_q straight-through + masked loss ----
__global__ __launch_bounds__(256, 2) void k_post(const float* __restrict__ z,
                                                 const float* __restrict__ emb,
                                                 const float* __restrict__ mask,
                                                 const float* __restrict__ e2g,
                                                 const unsigned short* __restrict__ cand_codes,
                                                 const unsigned* __restrict__ cand_cnt,
                                                 int* __restrict__ idxw,
                                                 unsigned* __restrict__ counts,
                                                 float* __restrict__ idx_out,
                                                 float* __restrict__ zq_out,
                                                 float* __restrict__ lp) {
  __shared__ float zs[256][34];          // 34.8 KB  [k][p]
  __shared__ float eq[256][34];          // 34.8 KB  [c][p] winner rows
  __shared__ double zpart[32][9];        // 2.3 KB   z2 fp64 partials
  __shared__ unsigned long long bestkey[32];
  __shared__ float z2s[32];
  __shared__ int ids[32];
  __shared__ unsigned char dcnt[32];
  __shared__ int bad[32];
  __shared__ int nbad;
  __shared__ float red[256];
  __shared__ int rdi[256];

  const int tid = threadIdx.x, bid = blockIdx.x;
  const int b = bid >> 5, l0 = (bid & 31) << 5, n0 = bid << 5;

  // stage zs[k][p] = z[b][k][l0+p]  (float4 coalesced along l)
  {
    const float4* z4 = reinterpret_cast<const float4*>(z + (size_t)b * C_ * L_ + l0);
    const int l4 = tid & 7, kk = tid >> 3;
#pragma unroll
    for (int rep = 0; rep < 8; ++rep) {
      int k = rep * 32 + kk;
      float4 v = z4[(size_t)k * (L_ / 4) + l4];
      *reinterpret_cast<float4*>(&zs[k][l4 * 4]) = v;
    }
  }
  if (tid == 0) nbad = 0;
  __syncthreads();

  // parallel z2 partials: 8 threads/point, fp64 (order-insensitive at fp32)
  {
    const int p = tid >> 3, j = tid & 7;
    double s = 0.0;
#pragma unroll 8
    for (int k = j * 32; k < j * 32 + 32; ++k) {
      float v = zs[k][p];
      s += (double)v * (double)v;
    }
    zpart[p][j] = s;
  }
  __syncthreads();

  // merge z2 + classify
  if (tid < 32) {
    const int n = n0 + tid;
    double s = 0.0;
#pragma unroll
    for (int j = 0; j < 8; ++j) s += zpart[tid][j];
    z2s[tid] = (float)s;
    bestkey[tid] = ~0ULL;
    const unsigned cnt = cand_cnt[n];
    if (cnt == 1u) {
      dcnt[tid] = 0;
      ids[tid] = cand_codes[(size_t)n * 32];
    } else if (cnt >= 2u && cnt <= 32u) {
      dcnt[tid] = (unsigned char)cnt;
    } else {
      dcnt[tid] = 0;
      bad[atomicAdd(&nbad, 1)] = tid;
    }
  }
  __syncthreads();

  // exact dots: 8 threads per point (sequential-k fmaf chain, bit-matches R1-R6)
  {
    const int p = tid >> 3, j = tid & 7;
    const int cnt = dcnt[p];
    const int n = n0 + p;
    for (int q = j; q < cnt; q += 8) {
      const int c = cand_codes[(size_t)n * 32 + q];
      const float4* er = reinterpret_cast<const float4*>(emb + (size_t)c * C_);
      float acc = 0.f;
#pragma unroll 4
      for (int k4 = 0; k4 < 64; ++k4) {
        float4 e = er[k4];
        acc = fmaf(zs[k4 * 4 + 0][p], e.x, acc);
        acc = fmaf(zs[k4 * 4 + 1][p], e.y, acc);
        acc = fmaf(zs[k4 * 4 + 2][p], e.z, acc);
        acc = fmaf(zs[k4 * 4 + 3][p], e.w, acc);
      }
      const float d = (z2s[p] + e2g[c]) - 2.0f * acc;   // numpy op order
      const unsigned long long key = ((unsigned long long)fkey(d) << 32) | (unsigned)c;
      atomicMin(&bestkey[p], key);
    }
  }
  __syncthreads();
  if (tid < 32 && dcnt[tid]) ids[tid] = (int)(unsigned)(bestkey[tid] & 0xFFFFFFFFu);

  // rare fallback: block-wide exact full scan for overflowed points
  if (nbad > 0) {
    __syncthreads();
    for (int ib = 0; ib < nbad; ++ib) {
      const int p = bad[ib];
      float bd = 3.4e38f;
      int bi = 0x7fffffff;
      for (int c = tid * 4; c < tid * 4 + 4; ++c) {
        const float* er = emb + (size_t)c * C_;
        float acc = 0.f;
        for (int k = 0; k < 256; ++k) acc = fmaf(zs[k][p], er[k], acc);
        const float d = (z2s[p] + e2g[c]) - 2.0f * acc;
        if (d < bd || (d == bd && c < bi)) { bd = d; bi = c; }
      }
      red[tid] = bd; rdi[tid] = bi;
      __syncthreads();
      for (int off = 128; off > 0; off >>= 1) {
        if (tid < off) {
          if (red[tid + off] < red[tid] ||
              (red[tid + off] == red[tid] && rdi[tid + off] < rdi[tid])) {
            red[tid] = red[tid + off]; rdi[tid] = rdi[tid + off];
          }
        }
        __syncthreads();
      }
      if (tid == 0) ids[p] = rdi[0];
      __syncthreads();
    }
  }
  __syncthreads();

  // finalize winners
  if (tid < 32) {
    const int n = n0 + tid;
    const int id = ids[tid];
    idxw[n] = id;
    idx_out[n] = (float)id;
    atomicAdd(&counts[id], 1u);
  }
  __syncthreads();

  // stage winner emb rows: eq[c][p]
  {
    const int r = tid >> 3, kq = tid & 7;
    const float4* e4 = reinterpret_cast<const float4*>(emb + (size_t)ids[r] * C_);
#pragma unroll
    for (int rep = 0; rep < 8; ++rep) {
      int c4 = rep * 8 + kq;
      float4 v = e4[c4];
      eq[c4 * 4 + 0][r] = v.x;
      eq[c4 * 4 + 1][r] = v.y;
      eq[c4 * 4 + 2][r] = v.z;
      eq[c4 * 4 + 3][r] = v.w;
    }
  }
  __syncthreads();

  // z_q straight-through + masked loss partials
  {
    const int lq = tid & 31, cg = tid >> 5;
    const float m = mask[b * L_ + l0 + lq];
    const size_t zbase = (size_t)b * C_ * L_ + l0 + lq;
    float s = 0.f;
#pragma unroll 4
    for (int ci = 0; ci < 32; ++ci) {
      int c = cg * 32 + ci;
      float zv = zs[c][lq];
      float q  = eq[c][lq];
      float diff = q - zv;                          // fl(z_q - zp)
      zq_out[zbase + (size_t)c * L_] = zv + diff;   // straight-through
      float t = diff * m;
      s = fmaf(t, t, s);
    }
    red[tid] = s;
  }
  __syncthreads();
  for (int off = 128; off > 0; off >>= 1) {
    if (tid < off) red[tid] += red[tid + off];
    __syncthreads();
  }
  if (tid == 0) lp[bid] = red[0];
}

// ---- one_hot: single pass, values on the fly (base only 8B-aligned) ----
__global__ __launch_bounds__(256) void k_onehot(const int* __restrict__ idxw,
                                                float* __restrict__ oh) {
  const int tid = threadIdx.x, bid = blockIdx.x;
#pragma unroll
  for (int r = 0; r < 16; ++r) {
    const int n = bid * 16 + r;
    const int id = idxw[n];
    float* row = oh + (size_t)n * NE;
    const int c = tid * 4;
    float2 v0, v1;
    v0.x = (c + 0 == id) ? 1.f : 0.f;
    v0.y = (c + 1 == id) ? 1.f : 0.f;
    v1.x = (c + 2 == id) ? 1.f : 0.f;
    v1.y = (c + 3 == id) ? 1.f : 0.f;
    *reinterpret_cast<float2*>(row + c)     = v0;
    *reinterpret_cast<float2*>(row + c + 2) = v1;
  }
}

// ---- deterministic loss total + perplexity ----
__global__ __launch_bounds__(256) void k_final(const float* __restrict__ lp,
                                               const unsigned int* __restrict__ counts,
                                               float* __restrict__ out) {
  __shared__ float red[256];
  const int t = threadIdx.x;
  red[t] = lp[t] + lp[t + 256] + lp[t + 512] + lp[t + 768];
  __syncthreads();
  for (int off = 128; off > 0; off >>= 1) {
    if (t < off) red[t] += red[t + off];
    __syncthreads();
  }
  if (t == 0) {
    float m = red[0] / 8388608.0f;
    out[LOSS_OFF] = m + 0.25f * m;
  }
  __syncthreads();
  float h = 0.f;
#pragma unroll
  for (int q = 0; q < 4; ++q) {
    int jj = t * 4 + q;
    float em = (float)counts[jj] * (1.0f / 32768.0f);
    h += em * logf(em + 1e-10f);
  }
  red[t] = h;
  __syncthreads();
  for (int off = 128; off > 0; off >>= 1) {
    if (t < off) red[t] += red[t + off];
    __syncthreads();
  }
  if (t == 0) out[PERP_OFF] = expf(-red[0]);
}

extern "C" void kernel_launch(void* const* d_in, const int* in_sizes, int n_in,
                              void* d_out, int out_size, void* d_ws, size_t ws_size,
                              hipStream_t stream) {
  const float* z    = (const float*)d_in[0];
  const float* mask = (const float*)d_in[1];
  const float* emb  = (const float*)d_in[2];
  float* out = (float*)d_out;
  char* ws = (char*)d_ws;
  int* idxw            = (int*)(ws + WS_IDX);
  unsigned int* counts = (unsigned int*)(ws + WS_CNT);
  float* lp            = (float*)(ws + WS_LP);
  float* e2            = (float*)(ws + WS_E2);

  // big scratch inside the one_hot output region; k_onehot (which overwrites
  // it) runs strictly after all readers on the same stream.
  uintptr_t sp = (uintptr_t)(out + OH_OFF);
  sp = (sp + 15) & ~(uintptr_t)15;
  _Float16* ehl              = (_Float16*)sp;                              // 512 KB
  unsigned short* cand_codes = (unsigned short*)(sp + 524288);             // 2 MB
  unsigned* cand_cnt         = (unsigned*)(sp + 524288 + 2097152);         // 128 KB

  hipLaunchKernelGGL(k_prep, dim3(256), dim3(256), 0, stream,
                     emb, ehl, e2, counts);
  hipLaunchKernelGGL(k_screen, dim3(512), dim3(512), 0, stream,
                     z, ehl, e2, cand_codes, cand_cnt);
  hipLaunchKernelGGL(k_post, dim3(1024), dim3(256), 0, stream,
                     z, emb, mask, e2, cand_codes, cand_cnt,
                     idxw, counts, out + IDX_OFF, out + ZQ_OFF, lp);
  hipLaunchKernelGGL(k_onehot, dim3(NPTS / 16), dim3(256), 0, stream,
                     idxw, out + OH_OFF);
  hipLaunchKernelGGL(k_final, dim3(1), dim3(256), 0, stream, lp, counts, out);
}

// Round 8
// 117.573 us; speedup vs baseline: 1.1540x; 1.1540x over previous
//
#include <hip/hip_runtime.h>

// Problem constants
constexpr int B_ = 32, C_ = 256, L_ = 1024, NE = 1024;
constexpr int NPTS = B_ * L_;            // 32768 points
// d_out flat float32 layout (reference return order)
constexpr long long LOSS_OFF = 0;
constexpr long long ZQ_OFF   = 1;                         // 8,388,608 elems
constexpr long long PERP_OFF = 1 + 8388608;               // 8388609
constexpr long long OH_OFF   = PERP_OFF + 1;              // 8388610
constexpr long long IDX_OFF  = OH_OFF + 33554432LL;       // 41943042
// workspace byte offsets
constexpr size_t WS_IDX = 0;            // int[32768]
constexpr size_t WS_CNT = 131072;       // uint[1024]
constexpr size_t WS_LP  = 135168;       // float[512]
constexpr size_t WS_E2  = 139264;       // float[1024]

constexpr float MARGIN = 7e-4f;         // >= 2*(fp16 dot err) + d-quantization slack

typedef _Float16 f16x8 __attribute__((ext_vector_type(8)));
typedef float    f32x4 __attribute__((ext_vector_type(4)));

__device__ inline unsigned fkey(float f) {
  unsigned u = __float_as_uint(f);
  return (u & 0x80000000u) ? ~u : (u | 0x80000000u);
}
__device__ inline float unfkey(unsigned k) {
  unsigned u = (k & 0x80000000u) ? (k ^ 0x80000000u) : ~k;
  return __uint_as_float(u);
}

// ---- prep A: codebook fp32 -> fp16 fragments, pre-swizzled MFMA-order ----
// ehlF unit u (uint4 = 8 f16): u = (g*32 + s8)*16 + c16, code = g*16+c16,
// k-range = s8*8..s8*8+7. Screen's bfr load over 16 lanes = 256B contiguous.
__global__ __launch_bounds__(256) void k_prep_ehl(const float* __restrict__ emb,
                                                  uint4* __restrict__ ehlF) {
  const int u = blockIdx.x * 256 + threadIdx.x;   // 32768 units
  const int c16 = u & 15;
  const int s8  = (u >> 4) & 31;
  const int g   = u >> 9;
  const int code = g * 16 + c16;
  const float4* e4 = reinterpret_cast<const float4*>(emb + (size_t)code * C_) + s8 * 2;
  float4 v0 = e4[0], v1 = e4[1];
  const float f[8] = {v0.x, v0.y, v0.z, v0.w, v1.x, v1.y, v1.z, v1.w};
  unsigned w[4];
#pragma unroll
  for (int i = 0; i < 4; ++i) {
    _Float16 h0 = (_Float16)f[2 * i];
    _Float16 h1 = (_Float16)f[2 * i + 1];
    w[i] = (unsigned)__builtin_bit_cast(unsigned short, h0) |
           ((unsigned)__builtin_bit_cast(unsigned short, h1) << 16);
  }
  ehlF[u] = make_uint4(w[0], w[1], w[2], w[3]);
}

// ---- prep B: e2 (fp64 chain, bit-matches R1-R7) + zero counts ----
__global__ __launch_bounds__(64) void k_prep_e2(const float* __restrict__ emb,
                                                float* __restrict__ e2,
                                                unsigned* __restrict__ counts) {
  const int j = blockIdx.x;
  const int t = threadIdx.x;
  const float* row = emb + (size_t)j * C_;
  double s = 0.0;
#pragma unroll
  for (int q = 0; q < 4; ++q) {
    float v = row[t + 64 * q];
    s += (double)v * (double)v;
  }
#pragma unroll
  for (int off = 32; off > 0; off >>= 1) s += __shfl_down(s, off);
  if (t == 0) { e2[j] = (float)s; counts[j] = 0u; }
}

// ---- fused MFMA screen + exact re-rank: 128 pts x 1024 codes per block ----
// Screen: same MFMA operand values/extraction as verified R6 (candidates
// identical). Re-rank in-block: cand stays in LDS; exact d replays the
// bit-identical sequential-k fp32 fmaf chain (z fp32 scattered from global,
// L2-hot; emb rows float4); winner via packed-key LDS atomicMin.
__global__ __launch_bounds__(512, 1) void k_screen_rr(const float* __restrict__ z,
                                                      const float* __restrict__ emb,
                                                      const uint4* __restrict__ ehlF,
                                                      const float* __restrict__ e2g,
                                                      int* __restrict__ idxw,
                                                      unsigned* __restrict__ counts,
                                                      float* __restrict__ idx_out) {
  __shared__ _Float16 Az[128 * 256];          // 64 KB
  __shared__ double zpart[128][17];           // 17.4 KB (fp64 z2 partials)
  __shared__ unsigned short cand[128 * 32];   // 8 KB
  __shared__ unsigned long long bestkey[128]; // 1 KB
  __shared__ unsigned minkey[128];
  __shared__ unsigned ccnt[128];
  __shared__ float z2s[128];
  __shared__ int ids[128];
  __shared__ unsigned char dcnt[128];
  __shared__ float zcol[256];
  __shared__ int nbad;

  const int tid  = threadIdx.x;
  const int lane = tid & 63;
  const int wid  = tid >> 6;
  const int wr   = wid >> 2;          // 0..1 point half
  const int wc   = wid & 3;           // 0..3 code quarter (of chunk)
  const int l15  = lane & 15;
  const int lhi  = lane >> 4;         // 0..3
  const int n0   = blockIdx.x * 128;
  const int b    = blockIdx.x >> 3;
  const int l0   = (blockIdx.x & 7) << 7;

  // A transpose+convert (R6-verbatim) + fp64 z2 partials
  {
    const float4* z4 = reinterpret_cast<const float4*>(z + (size_t)b * (C_ * L_) + l0);
    const int l4 = tid & 31;
    const int kp = tid >> 5;            // 0..15
    double sj[4] = {0.0, 0.0, 0.0, 0.0};
#pragma unroll
    for (int rr = 0; rr < 8; ++rr) {
      const int k0 = rr * 32 + kp * 2;
      float4 a0 = z4[(size_t)k0 * (L_ / 4) + l4];
      float4 a1 = z4[(size_t)(k0 + 1) * (L_ / 4) + l4];
      const float av0[4] = {a0.x, a0.y, a0.z, a0.w};
      const float av1[4] = {a1.x, a1.y, a1.z, a1.w};
#pragma unroll
      for (int j = 0; j < 4; ++j) {
        _Float16 h0 = (_Float16)av0[j];
        _Float16 h1 = (_Float16)av1[j];
        unsigned pk = (unsigned)__builtin_bit_cast(unsigned short, h0) |
                      ((unsigned)__builtin_bit_cast(unsigned short, h1) << 16);
        const int p = l4 * 4 + j;
        const int slot = k0 >> 3;
        const int addr = p * 256 + ((slot ^ (p & 31)) << 3) + (k0 & 7);
        *reinterpret_cast<unsigned*>(&Az[addr]) = pk;
        sj[j] += (double)av0[j] * (double)av0[j];
        sj[j] += (double)av1[j] * (double)av1[j];
      }
    }
#pragma unroll
    for (int j = 0; j < 4; ++j) zpart[l4 * 4 + j][kp] = sj[j];
  }
  if (tid < 128) { minkey[tid] = 0xFFFFFFFFu; ccnt[tid] = 0u; }
  if (tid == 0) nbad = 0;
  __syncthreads();

  f32x4 acc[4][4];
#pragma unroll
  for (int i = 0; i < 4; ++i)
#pragma unroll
    for (int j = 0; j < 4; ++j) acc[i][j] = (f32x4){0.f, 0.f, 0.f, 0.f};

  for (int ph = 0; ph < 8; ++ph) {
    const int cc = ph >> 1;
    const int kh = ph & 1;
#pragma unroll
    for (int s = 0; s < 4; ++s) {
      const int slotA = kh * 16 + s * 4 + lhi;
      const int slotB = kh * 16 + s * 4 + lhi;
      // B fragments from pre-swizzled ehlF: 16 lanes = 256B contiguous
      f16x8 bfr[4];
#pragma unroll
      for (int tj = 0; tj < 4; ++tj) {
        const int g = cc * 16 + wc * 4 + tj;
        bfr[tj] = __builtin_bit_cast(f16x8, ehlF[(g * 32 + slotB) * 16 + l15]);
      }
      f16x8 afr[4];
#pragma unroll
      for (int ti = 0; ti < 4; ++ti) {
        const int pA = wr * 64 + ti * 16 + l15;
        const int swzA = slotA ^ (((ti & 1) << 4) ^ l15);
        afr[ti] = *reinterpret_cast<const f16x8*>(&Az[pA * 256 + swzA * 8]);
      }
#pragma unroll
      for (int ti = 0; ti < 4; ++ti)
#pragma unroll
        for (int tj = 0; tj < 4; ++tj)
          acc[ti][tj] = __builtin_amdgcn_mfma_f32_16x16x32_f16(
              afr[ti], bfr[tj], acc[ti][tj], 0, 0, 0);
    }
    if (kh == 1) {
      float e2r[4];
#pragma unroll
      for (int tj = 0; tj < 4; ++tj)
        e2r[tj] = e2g[cc * 256 + wc * 64 + tj * 16 + l15];
#pragma unroll
      for (int ti = 0; ti < 4; ++ti) {
#pragma unroll
        for (int r = 0; r < 4; ++r) {
          float m = e2r[0] - 2.0f * acc[ti][0][r];
#pragma unroll
          for (int tj = 1; tj < 4; ++tj) {
            float v = e2r[tj] - 2.0f * acc[ti][tj][r];
            m = fminf(m, v);
          }
          m = fminf(m, __shfl_xor(m, 1));
          m = fminf(m, __shfl_xor(m, 2));
          m = fminf(m, __shfl_xor(m, 4));
          m = fminf(m, __shfl_xor(m, 8));
          if (l15 == 0) {
            const int p = wr * 64 + ti * 16 + lhi * 4 + r;
            atomicMin(&minkey[p], fkey(m));
          }
        }
      }
      __syncthreads();   // chunk mins visible; later chunks only shrink thr
#pragma unroll
      for (int ti = 0; ti < 4; ++ti) {
#pragma unroll
        for (int r = 0; r < 4; ++r) {
          const int p = wr * 64 + ti * 16 + lhi * 4 + r;
          const float thr = unfkey(minkey[p]) + MARGIN;
#pragma unroll
          for (int tj = 0; tj < 4; ++tj) {
            float s = e2r[tj] - 2.0f * acc[ti][tj][r];
            if (s <= thr) {
              unsigned pos = atomicAdd(&ccnt[p], 1u);
              if (pos < 32u)
                cand[p * 32 + pos] = (unsigned short)(cc * 256 + wc * 64 + tj * 16 + l15);
            }
          }
        }
      }
#pragma unroll
      for (int i = 0; i < 4; ++i)
#pragma unroll
        for (int j = 0; j < 4; ++j) acc[i][j] = (f32x4){0.f, 0.f, 0.f, 0.f};
    }
  }
  __syncthreads();

  // ---- re-rank phase (in-block) ----
  if (tid < 128) {
    double s = 0.0;
#pragma unroll
    for (int kp = 0; kp < 16; ++kp) s += zpart[tid][kp];
    z2s[tid] = (float)s;
    bestkey[tid] = ~0ULL;
    const unsigned cnt = ccnt[tid];
    if (cnt == 1u) {
      dcnt[tid] = 0;
      ids[tid] = cand[tid * 32];
    } else if (cnt <= 32u) {           // 2..32
      dcnt[tid] = (unsigned char)cnt;
    } else {                           // overflow -> block full scan
      dcnt[tid] = 0xFF;
      atomicAdd(&nbad, 1);
    }
  }
  __syncthreads();

  // exact pair dots: 4 threads/point; sequential-k fmaf chain (bit-exact)
  {
    const int p = tid >> 2, j = tid & 3;
    const int cnt = (dcnt[p] == 0xFF) ? 0 : (int)dcnt[p];
    const float* zc = z + (size_t)b * (C_ * L_) + l0 + p;
    for (int q = j; q < cnt; q += 4) {
      const int c = cand[p * 32 + q];
      const float4* er = reinterpret_cast<const float4*>(emb + (size_t)c * C_);
      float acc2 = 0.f;
#pragma unroll 4
      for (int k4 = 0; k4 < 64; ++k4) {
        float4 e = er[k4];
        acc2 = fmaf(zc[(size_t)(k4 * 4 + 0) * L_], e.x, acc2);
        acc2 = fmaf(zc[(size_t)(k4 * 4 + 1) * L_], e.y, acc2);
        acc2 = fmaf(zc[(size_t)(k4 * 4 + 2) * L_], e.z, acc2);
        acc2 = fmaf(zc[(size_t)(k4 * 4 + 3) * L_], e.w, acc2);
      }
      const float d = (z2s[p] + e2g[c]) - 2.0f * acc2;   // numpy op order
      const unsigned long long key =
          ((unsigned long long)fkey(d) << 32) | (unsigned)c;
      atomicMin(&bestkey[p], key);
    }
  }
  __syncthreads();

  // rare overflow fallback: full 1024-code scan, block-cooperative
  if (nbad > 0) {
    for (int p = 0; p < 128; ++p) {
      if (dcnt[p] != 0xFF) continue;
      const float* zc = z + (size_t)b * (C_ * L_) + l0 + p;
      if (tid < 256) zcol[tid] = zc[(size_t)tid * L_];
      __syncthreads();
#pragma unroll
      for (int h = 0; h < 2; ++h) {
        const int c = tid * 2 + h;
        const float* er = emb + (size_t)c * C_;
        float acc2 = 0.f;
        for (int k = 0; k < 256; ++k) acc2 = fmaf(zcol[k], er[k], acc2);
        const float d = (z2s[p] + e2g[c]) - 2.0f * acc2;
        const unsigned long long key =
            ((unsigned long long)fkey(d) << 32) | (unsigned)c;
        atomicMin(&bestkey[p], key);
      }
      __syncthreads();
    }
  }

  // finalize winners
  if (tid < 128) {
    const int n = n0 + tid;
    int id = ids[tid];
    if (dcnt[tid] != 0) id = (int)(unsigned)(bestkey[tid] & 0xFFFFFFFFu);
    idxw[n] = id;
    idx_out[n] = (float)id;
    atomicAdd(&counts[id], 1u);
  }
}

// ---- gather (z_q straight-through) + masked loss partials (R5-verified) ----
__global__ __launch_bounds__(256) void k_zq_loss(const float* __restrict__ z,
                                                 const float* __restrict__ emb,
                                                 const float* __restrict__ mask,
                                                 const int* __restrict__ idxw,
                                                 float* __restrict__ zq_out,
                                                 float* __restrict__ lp) {
  __shared__ float eq[256][66];
  __shared__ float red[256];
  const int tid = threadIdx.x, bid = blockIdx.x;
  const int b = bid >> 4, l0 = (bid & 15) << 6, n0 = bid << 6;
  {
    const int r  = tid >> 2;
    const int kq = tid & 3;
    const int id = idxw[n0 + r];
    const float4* e4 = reinterpret_cast<const float4*>(emb + (size_t)id * C_);
#pragma unroll
    for (int rep = 0; rep < 16; ++rep) {
      int c4 = rep * 4 + kq;
      float4 v = e4[c4];
      eq[c4 * 4 + 0][r] = v.x;
      eq[c4 * 4 + 1][r] = v.y;
      eq[c4 * 4 + 2][r] = v.z;
      eq[c4 * 4 + 3][r] = v.w;
    }
  }
  __syncthreads();
  const int lq = tid & 63, cg = tid >> 6;
  const float m = mask[b * L_ + l0 + lq];
  const size_t zbase = (size_t)b * C_ * L_ + l0 + lq;
  float s = 0.f;
#pragma unroll 4
  for (int ci = 0; ci < 64; ++ci) {
    int c = cg * 64 + ci;
    float zv = z[zbase + (size_t)c * L_];
    float q  = eq[c][lq];
    float diff = q - zv;                         // fl(z_q - zp)
    zq_out[zbase + (size_t)c * L_] = zv + diff;  // straight-through
    float t = diff * m;
    s = fmaf(t, t, s);
  }
  red[tid] = s;
  __syncthreads();
  for (int off = 128; off > 0; off >>= 1) {
    if (tid < off) red[tid] += red[tid + off];
    __syncthreads();
  }
  if (tid == 0) lp[bid] = red[0];
}

// ---- one_hot: single pass, values on the fly (base only 8B-aligned) ----
__global__ __launch_bounds__(256) void k_onehot(const int* __restrict__ idxw,
                                                float* __restrict__ oh) {
  const int tid = threadIdx.x, bid = blockIdx.x;
#pragma unroll
  for (int r = 0; r < 16; ++r) {
    const int n = bid * 16 + r;
    const int id = idxw[n];
    float* row = oh + (size_t)n * NE;
    const int c = tid * 4;
    float2 v0, v1;
    v0.x = (c + 0 == id) ? 1.f : 0.f;
    v0.y = (c + 1 == id) ? 1.f : 0.f;
    v1.x = (c + 2 == id) ? 1.f : 0.f;
    v1.y = (c + 3 == id) ? 1.f : 0.f;
    *reinterpret_cast<float2*>(row + c)     = v0;
    *reinterpret_cast<float2*>(row + c + 2) = v1;
  }
}

// ---- deterministic loss total + perplexity (lp: 512 entries) ----
__global__ __launch_bounds__(256) void k_final(const float* __restrict__ lp,
                                               const unsigned int* __restrict__ counts,
                                               float* __restrict__ out) {
  __shared__ float red[256];
  const int t = threadIdx.x;
  red[t] = lp[t] + lp[t + 256];
  __syncthreads();
  for (int off = 128; off > 0; off >>= 1) {
    if (t < off) red[t] += red[t + off];
    __syncthreads();
  }
  if (t == 0) {
    float m = red[0] / 8388608.0f;
    out[LOSS_OFF] = m + 0.25f * m;
  }
  __syncthreads();
  float h = 0.f;
#pragma unroll
  for (int q = 0; q < 4; ++q) {
    int jj = t * 4 + q;
    float em = (float)counts[jj] * (1.0f / 32768.0f);
    h += em * logf(em + 1e-10f);
  }
  red[t] = h;
  __syncthreads();
  for (int off = 128; off > 0; off >>= 1) {
    if (t < off) red[t] += red[t + off];
    __syncthreads();
  }
  if (t == 0) out[PERP_OFF] = expf(-red[0]);
}

extern "C" void kernel_launch(void* const* d_in, const int* in_sizes, int n_in,
                              void* d_out, int out_size, void* d_ws, size_t ws_size,
                              hipStream_t stream) {
  const float* z    = (const float*)d_in[0];
  const float* mask = (const float*)d_in[1];
  const float* emb  = (const float*)d_in[2];
  float* out = (float*)d_out;
  char* ws = (char*)d_ws;
  int* idxw            = (int*)(ws + WS_IDX);
  unsigned int* counts = (unsigned int*)(ws + WS_CNT);
  float* lp            = (float*)(ws + WS_LP);
  float* e2            = (float*)(ws + WS_E2);

  // ehlF scratch lives in the one_hot output region; k_onehot (the only
  // writer of that region) runs strictly after k_screen_rr on the stream.
  uintptr_t sp = (uintptr_t)(out + OH_OFF);
  sp = (sp + 15) & ~(uintptr_t)15;
  uint4* ehlF = (uint4*)sp;                                 // 512 KB

  hipLaunchKernelGGL(k_prep_ehl, dim3(128), dim3(256), 0, stream, emb, ehlF);
  hipLaunchKernelGGL(k_prep_e2, dim3(NE), dim3(64), 0, stream, emb, e2, counts);
  hipLaunchKernelGGL(k_screen_rr, dim3(256), dim3(512), 0, stream,
                     z, emb, ehlF, e2, idxw, counts, out + IDX_OFF);
  hipLaunchKernelGGL(k_zq_loss, dim3(512), dim3(256), 0, stream,
                     z, emb, mask, idxw, out + ZQ_OFF, lp);
  hipLaunchKernelGGL(k_onehot, dim3(NPTS / 16), dim3(256), 0, stream,
                     idxw, out + OH_OFF);
  hipLaunchKernelGGL(k_final, dim3(1), dim3(256), 0, stream, lp, counts, out);
}